// Round 2
// baseline (1685.844 us; speedup 1.0000x reference)
//
#include <hip/hip_runtime.h>
#include <hip/hip_fp16.h>

// DNCClassifier: DNC memory machinery is dead code (inputs built with the
// initial zero read vector); output = LSTM-final-h @ W_fc.T + b_fc.
//   gates_t = x_t @ W_ih[:, :27].T + (b_ih + b_hh) + h @ W_hh.T
// Sizes: B=128, T=512, IN=27, H=256 (4H=1024), OUT=128.
//
// R2 design (fixes R1's AGPR spill: arch VGPRs cap at 256/wave):
//  - 512 thr/block, 2 waves/SIMD. K-split: thread v<256 does k[0:128) of
//    unit v's 4 gate rows; thread v+256 does k[128:256). Partials merged
//    through LDS; low thread owns c,h.
//  - weights: 13 quads/row (208 VGPRs) resident; last 3 quads/row streamed
//    from L2 every step (96 KB/CU/step, VMEM pipe, tail region L2-resident).
//  - sH double-buffered (2 barriers/step); bias folded into P in prep.

typedef _Float16 h2t __attribute__((ext_vector_type(2)));

#if defined(__has_builtin)
#  if __has_builtin(__builtin_amdgcn_fdot2)
#    define HAVE_FDOT2 1
#  endif
#endif

__device__ __forceinline__ h2t bc2(unsigned int v) {
  union { unsigned int u; h2t h; } x; x.u = v; return x.h;
}
__device__ __forceinline__ unsigned int pk(float a, float b) {
  union { h2t h; unsigned int u; } x;
  x.h[0] = (_Float16)a; x.h[1] = (_Float16)b;
  return x.u;
}
__device__ __forceinline__ float fdot2f(h2t a, h2t b, float c) {
#ifdef HAVE_FDOT2
  return __builtin_amdgcn_fdot2(a, b, c, false);
#else
  return c + (float)a[0] * (float)b[0] + (float)a[1] * (float)b[1];
#endif
}
__device__ __forceinline__ float sigmf_(float x) {
  return 1.f / (1.f + __expf(-x));
}
__device__ __forceinline__ float tanhf_(float x) {
  float xc = fminf(15.f, fmaxf(-15.f, x));
  float e = __expf(2.f * xc);
  return (e - 1.f) / (e + 1.f);
}

// ---- workspace layout (bytes) ----
// P      : [(t*128+b)*256+u] uint2 (4 halves: gates i,f,g,o incl. bias)
// Wscan  : uint4[(g*13+q)*512+v]  -> VGPR-resident weights, k2=(v>>8)*64+4q+e
// Wtail  : uint4[(g*3+qq)*512+v]  -> per-step streamed,     k2=(v>>8)*64+52+4qq+e
#define WS_P_OFF      0ull
#define WS_WSCAN_OFF  134217728ull
#define WS_WTAIL_OFF  134643712ull
#define WS_NEED       134742016ull

__global__ void prep_w(const float* __restrict__ W_hh,
                       unsigned char* __restrict__ ws) {
  int idx = blockIdx.x * 256 + threadIdx.x;   // 512 blocks -> idx < 131072
  if (idx < 106496) {                         // Wscan: 4*13*512 quads = 106496 uints
    int e = idx & 3; int rest = idx >> 2;     // rest = (g*13+q)*512 + v
    int v = rest & 511; int gq = rest >> 9;
    int g = gq / 13, q = gq - 13 * g;
    int k2 = ((v >> 8) << 6) + 4 * q + e;     // base 0 or 64
    int r = g * 256 + (v & 255);
    ((unsigned int*)(ws + WS_WSCAN_OFF))[idx] =
        pk(W_hh[r * 256 + 2 * k2], W_hh[r * 256 + 2 * k2 + 1]);
  } else {                                    // Wtail: 4*3*512 quads = 24576 uints
    int j = idx - 106496;
    int e = j & 3; int rest = j >> 2;         // rest = (g*3+qq)*512 + v
    int v = rest & 511; int gq = rest >> 9;
    int g = gq / 3, qq = gq - 3 * g;
    int k2 = ((v >> 8) << 6) + 52 + 4 * qq + e;
    int r = g * 256 + (v & 255);
    ((unsigned int*)(ws + WS_WTAIL_OFF))[j] =
        pk(W_hh[r * 256 + 2 * k2], W_hh[r * 256 + 2 * k2 + 1]);
  }
}

// P[t,b,u,g] = bias_g(u) + sum_c x[b,t,c] * W_ih[g*256+u, c], c<27 (fp16 out)
__global__ __launch_bounds__(256) void prep_p(const float* __restrict__ x,
                                              const float* __restrict__ W_ih,
                                              const float* __restrict__ b_ih,
                                              const float* __restrict__ b_hh,
                                              unsigned char* __restrict__ ws) {
  __shared__ unsigned int sX[16];
  const int u = threadIdx.x;
  unsigned int wih[4][14];
  float bias[4];
#pragma unroll
  for (int g = 0; g < 4; ++g) {
    const float* row = W_ih + (size_t)(g * 256 + u) * 47;
    bias[g] = b_ih[g * 256 + u] + b_hh[g * 256 + u];
#pragma unroll
    for (int j = 0; j < 14; ++j) {
      float a = row[2 * j];
      float b = (2 * j + 1 < 27) ? row[2 * j + 1] : 0.f;
      wih[g][j] = pk(a, b);
    }
  }
  uint2* Pout = (uint2*)(ws + WS_P_OFF);
#pragma unroll 1
  for (int p = 0; p < 64; ++p) {
    int idx = blockIdx.x * 64 + p;            // idx = t*128 + b
    int t = idx >> 7, b = idx & 127;
    __syncthreads();
    if (u < 14) {
      const float* xr = x + ((size_t)b * 512 + t) * 27;
      float a = xr[2 * u];
      float bb = (2 * u + 1 < 27) ? xr[2 * u + 1] : 0.f;
      sX[u] = pk(a, bb);
    }
    __syncthreads();
    float acc[4] = {bias[0], bias[1], bias[2], bias[3]};
#pragma unroll
    for (int j = 0; j < 14; ++j) {
      h2t xx = bc2(sX[j]);
#pragma unroll
      for (int g = 0; g < 4; ++g) acc[g] = fdot2f(bc2(wih[g][j]), xx, acc[g]);
    }
    uint2 o;
    o.x = pk(acc[0], acc[1]);
    o.y = pk(acc[2], acc[3]);
    Pout[(size_t)idx * 256 + u] = o;
  }
}

// Persistent LSTM scan. grid=128 (one block per batch element), 512 threads.
__global__ __launch_bounds__(512, 2) void scan_k(
    const unsigned char* __restrict__ ws, const float* __restrict__ W_fc,
    const float* __restrict__ b_fc, float* __restrict__ out) {
  __shared__ __align__(16) uint4 sHq[2][32];   // h double buffer, 32 quads each
  __shared__ __align__(16) float4 sAcc[256];   // high->low partial exchange
  __shared__ __align__(16) float sHF[256];     // final h fp32 for head
  const int v = threadIdx.x;
  const int b = blockIdx.x;
  const int half = v >> 8;                     // 0: k[0:128), 1: k[128:256)
  const int u = v & 255;

  // resident weights: 4 gates x 13 quads = 208 VGPRs
  uint4 wq[4][13];
  {
    const uint4* wsc = (const uint4*)(ws + WS_WSCAN_OFF);
#pragma unroll
    for (int g = 0; g < 4; ++g)
#pragma unroll
      for (int q = 0; q < 13; ++q) wq[g][q] = wsc[(g * 13 + q) * 512 + v];
  }
  const uint4* wtail = (const uint4*)(ws + WS_WTAIL_OFF);

  if (v < 64) ((uint4*)sHq)[v] = make_uint4(0u, 0u, 0u, 0u);  // h buffers = 0

  const uint2* Pbuf = (const uint2*)(ws + WS_P_OFF);
  uint2 pP = make_uint2(0u, 0u);
  if (half == 0) pP = Pbuf[(size_t)b * 256 + u];  // t=0 prefetch (low only)
  float c = 0.f, hval = 0.f;
  __syncthreads();

#pragma unroll 1
  for (int t = 0; t < 512; ++t) {
    // streamed tail weights (L2-resident, coalesced 16B/lane)
    uint4 tw[4][3];
#pragma unroll
    for (int g = 0; g < 4; ++g)
#pragma unroll
      for (int qq = 0; qq < 3; ++qq) tw[g][qq] = wtail[(g * 3 + qq) * 512 + v];

    const uint4* rd = &sHq[t & 1][half << 4];
    float acc0 = 0.f, acc1 = 0.f, acc2 = 0.f, acc3 = 0.f;
#pragma unroll
    for (int q = 0; q < 13; ++q) {             // k2 offsets 0..51 (VGPR weights)
      uint4 hq = rd[q];
      h2t h0 = bc2(hq.x), h1 = bc2(hq.y), h2v = bc2(hq.z), h3 = bc2(hq.w);
      acc0 = fdot2f(bc2(wq[0][q].x), h0, acc0);
      acc0 = fdot2f(bc2(wq[0][q].y), h1, acc0);
      acc0 = fdot2f(bc2(wq[0][q].z), h2v, acc0);
      acc0 = fdot2f(bc2(wq[0][q].w), h3, acc0);
      acc1 = fdot2f(bc2(wq[1][q].x), h0, acc1);
      acc1 = fdot2f(bc2(wq[1][q].y), h1, acc1);
      acc1 = fdot2f(bc2(wq[1][q].z), h2v, acc1);
      acc1 = fdot2f(bc2(wq[1][q].w), h3, acc1);
      acc2 = fdot2f(bc2(wq[2][q].x), h0, acc2);
      acc2 = fdot2f(bc2(wq[2][q].y), h1, acc2);
      acc2 = fdot2f(bc2(wq[2][q].z), h2v, acc2);
      acc2 = fdot2f(bc2(wq[2][q].w), h3, acc2);
      acc3 = fdot2f(bc2(wq[3][q].x), h0, acc3);
      acc3 = fdot2f(bc2(wq[3][q].y), h1, acc3);
      acc3 = fdot2f(bc2(wq[3][q].z), h2v, acc3);
      acc3 = fdot2f(bc2(wq[3][q].w), h3, acc3);
    }
#pragma unroll
    for (int qq = 0; qq < 3; ++qq) {           // k2 offsets 52..63 (streamed)
      uint4 hq = rd[13 + qq];
      h2t h0 = bc2(hq.x), h1 = bc2(hq.y), h2v = bc2(hq.z), h3 = bc2(hq.w);
      acc0 = fdot2f(bc2(tw[0][qq].x), h0, acc0);
      acc0 = fdot2f(bc2(tw[0][qq].y), h1, acc0);
      acc0 = fdot2f(bc2(tw[0][qq].z), h2v, acc0);
      acc0 = fdot2f(bc2(tw[0][qq].w), h3, acc0);
      acc1 = fdot2f(bc2(tw[1][qq].x), h0, acc1);
      acc1 = fdot2f(bc2(tw[1][qq].y), h1, acc1);
      acc1 = fdot2f(bc2(tw[1][qq].z), h2v, acc1);
      acc1 = fdot2f(bc2(tw[1][qq].w), h3, acc1);
      acc2 = fdot2f(bc2(tw[2][qq].x), h0, acc2);
      acc2 = fdot2f(bc2(tw[2][qq].y), h1, acc2);
      acc2 = fdot2f(bc2(tw[2][qq].z), h2v, acc2);
      acc2 = fdot2f(bc2(tw[2][qq].w), h3, acc2);
      acc3 = fdot2f(bc2(tw[3][qq].x), h0, acc3);
      acc3 = fdot2f(bc2(tw[3][qq].y), h1, acc3);
      acc3 = fdot2f(bc2(tw[3][qq].z), h2v, acc3);
      acc3 = fdot2f(bc2(tw[3][qq].w), h3, acc3);
    }

    uint2 pPn = pP;
    if (half) {
      sAcc[u] = make_float4(acc0, acc1, acc2, acc3);
    } else {
      int tn = (t < 511) ? (t + 1) : 511;
      pPn = Pbuf[((size_t)tn * 128 + b) * 256 + u];
    }
    __syncthreads();                           // sAcc visible; sH reads done

    if (!half) {
      float4 oth = sAcc[u];
      h2t p01 = bc2(pP.x), p23 = bc2(pP.y);
      float gi = acc0 + oth.x + (float)p01[0];
      float gf = acc1 + oth.y + (float)p01[1];
      float gg = acc2 + oth.z + (float)p23[0];
      float go = acc3 + oth.w + (float)p23[1];
      c = sigmf_(gf) * c + sigmf_(gi) * tanhf_(gg);
      hval = sigmf_(go) * tanhf_(c);
      ((_Float16*)(&sHq[(t + 1) & 1][0]))[u] = (_Float16)hval;
    }
    pP = pPn;
    __syncthreads();                           // h_{t+1} visible
  }

  // --- classifier head on final h ---
  if (!half) sHF[u] = hval;
  __syncthreads();
  if (v < 128) {
    const float4* wrow = (const float4*)(W_fc + (size_t)v * 256);
    float a = b_fc[v];
#pragma unroll 8
    for (int q = 0; q < 64; ++q) {
      float4 w = wrow[q];
      float4 hh = ((const float4*)sHF)[q];
      a += w.x * hh.x + w.y * hh.y + w.z * hh.z + w.w * hh.w;
    }
    out[(size_t)b * 128 + v] = a;
  }
}

extern "C" void kernel_launch(void* const* d_in, const int* in_sizes, int n_in,
                              void* d_out, int out_size, void* d_ws,
                              size_t ws_size, hipStream_t stream) {
  const float* x    = (const float*)d_in[0];
  // d_in[1] = input_lengths: unused by the reference
  const float* W_ih = (const float*)d_in[2];
  const float* W_hh = (const float*)d_in[3];
  const float* b_ih = (const float*)d_in[4];
  const float* b_hh = (const float*)d_in[5];
  // d_in[6] = W_xi, d_in[7] = b_xi: dead code in the reference
  const float* W_fc = (const float*)d_in[8];
  const float* b_fc = (const float*)d_in[9];
  unsigned char* ws = (unsigned char*)d_ws;

  if (ws_size < WS_NEED) return;  // signature: output stays poisoned

  prep_w<<<512, 256, 0, stream>>>(W_hh, ws);
  prep_p<<<1024, 256, 0, stream>>>(x, W_ih, b_ih, b_hh, ws);
  scan_k<<<128, 512, 0, stream>>>(ws, W_fc, b_fc, (float*)d_out);
}

// Round 3
// 902.748 us; speedup vs baseline: 1.8675x; 1.8675x over previous
//
#include <hip/hip_runtime.h>
#include <hip/hip_fp16.h>

// DNCClassifier: DNC memory machinery is dead code (inputs built with the
// initial zero read vector); output = LSTM-final-h @ W_fc.T + b_fc.
//   gates_t = x_t @ W_ih[:, :27].T + (b_ih + b_hh) + h @ W_hh.T
// Sizes: B=128, T=512, IN=27, H=256 (4H=1024), OUT=128.
//
// R3: R2's allocator demoted ALL weights to per-step L2 loads (VGPR_Count=128,
// ~7500 cyc/step, L2-BW bound). Now the 64 weight quads per thread are split
// into three tiers sized against measured BW:
//   42 quads VGPR (pinned with empty asm so they CANNOT be re-loaded),
//    7 quads LDS (57 KB resident, ~57 KB/step reads on 128 B/cyc pipe),
//   15 quads streamed from L2 per step (120 KB/step, overlaps 1024-cyc VALU).
// Flat weight-quad id f = q*4+g (q = h-quad 0..15, g = gate): f<42 VGPR,
// 42..48 LDS, 49..63 streamed.  k2 = (v>>8)*64 + 4q + e, row = g*256+(v&255).

typedef _Float16 h2t __attribute__((ext_vector_type(2)));
typedef unsigned int u32x4 __attribute__((ext_vector_type(4)));

#if defined(__has_builtin)
#  if __has_builtin(__builtin_amdgcn_fdot2)
#    define HAVE_FDOT2 1
#  endif
#endif

__device__ __forceinline__ h2t bc2(unsigned int v) {
  union { unsigned int u; h2t h; } x; x.u = v; return x.h;
}
__device__ __forceinline__ unsigned int pk(float a, float b) {
  union { h2t h; unsigned int u; } x;
  x.h[0] = (_Float16)a; x.h[1] = (_Float16)b;
  return x.u;
}
__device__ __forceinline__ float fdot2f(h2t a, h2t b, float c) {
#ifdef HAVE_FDOT2
  return __builtin_amdgcn_fdot2(a, b, c, false);
#else
  return c + (float)a[0] * (float)b[0] + (float)a[1] * (float)b[1];
#endif
}
__device__ __forceinline__ float dot4(u32x4 w, u32x4 h, float a) {
  a = fdot2f(bc2(w[0]), bc2(h[0]), a);
  a = fdot2f(bc2(w[1]), bc2(h[1]), a);
  a = fdot2f(bc2(w[2]), bc2(h[2]), a);
  a = fdot2f(bc2(w[3]), bc2(h[3]), a);
  return a;
}
__device__ __forceinline__ float sigmf_(float x) {
  return 1.f / (1.f + __expf(-x));
}
__device__ __forceinline__ float tanhf_(float x) {
  float xc = fminf(15.f, fmaxf(-15.f, x));
  float e = __expf(2.f * xc);
  return (e - 1.f) / (e + 1.f);
}

// ---- workspace layout (bytes) ----
// P      : [(t*128+b)*256+u] uint2 (gates i,f,g,o fp16, bias folded in)
// Wscan  : u32x4[fv*512+v], fv=f    (f<42)   -> VGPR-pinned
// Wlds   : u32x4[fl*512+v], fl=f-42 (42..48) -> LDS-resident
// Wstr   : u32x4[fs*512+v], fs=f-49 (49..63) -> streamed per step
#define WS_P_OFF      0ull
#define WS_WSCAN_OFF  134217728ull
#define WS_WLDS_OFF   134561792ull
#define WS_WSTR_OFF   134619136ull
#define WS_NEED       134742016ull

__global__ void prep_w(const float* __restrict__ W_hh,
                       unsigned char* __restrict__ ws) {
  int idx = blockIdx.x * 256 + threadIdx.x;   // 512 blocks -> idx < 131072
  unsigned int* dst; int j, f;
  if (idx < 86016) {                          // Wscan: 42*512*4 uints
    j = idx; dst = (unsigned int*)(ws + WS_WSCAN_OFF); f = (j >> 2) >> 9;
  } else if (idx < 100352) {                  // Wlds: 7*512*4 uints
    j = idx - 86016; dst = (unsigned int*)(ws + WS_WLDS_OFF);
    f = 42 + ((j >> 2) >> 9);
  } else {                                    // Wstr: 15*512*4 uints
    j = idx - 100352; dst = (unsigned int*)(ws + WS_WSTR_OFF);
    f = 49 + ((j >> 2) >> 9);
  }
  int e = j & 3, v = (j >> 2) & 511;
  int q = f >> 2, g = f & 3;
  int k2 = ((v >> 8) << 6) + 4 * q + e;
  int r = g * 256 + (v & 255);
  dst[j] = pk(W_hh[r * 256 + 2 * k2], W_hh[r * 256 + 2 * k2 + 1]);
}

// P[t,b,u,:] = bias(u,:) + x[b,t,:27] @ W_ih[:, :27].T  (fp16x4 out)
// grid 1024: block handles one t (= blockIdx>>1) x 64 b's. x staged up front.
__global__ __launch_bounds__(256) void prep_p(const float* __restrict__ x,
                                              const float* __restrict__ W_ih,
                                              const float* __restrict__ b_ih,
                                              const float* __restrict__ b_hh,
                                              unsigned char* __restrict__ ws) {
  __shared__ unsigned int sX[64][14];
  const int u = threadIdx.x;
  const int t = blockIdx.x >> 1;
  const int b0 = (blockIdx.x & 1) << 6;
  unsigned int wih[4][14];
  float bias[4];
#pragma unroll
  for (int g = 0; g < 4; ++g) {
    const float* row = W_ih + (size_t)(g * 256 + u) * 47;
    bias[g] = b_ih[g * 256 + u] + b_hh[g * 256 + u];
#pragma unroll
    for (int j = 0; j < 14; ++j) {
      float a = row[2 * j];
      float b = (2 * j + 1 < 27) ? row[2 * j + 1] : 0.f;
      wih[g][j] = pk(a, b);
    }
  }
#pragma unroll 1
  for (int j = u; j < 896; j += 256) {        // stage 64 rows of x
    int row = j / 14, c2 = j - 14 * row;
    const float* xr = x + ((size_t)(b0 + row) * 512 + t) * 27;
    float a = xr[2 * c2];
    float bb = (2 * c2 + 1 < 27) ? xr[2 * c2 + 1] : 0.f;
    sX[row][c2] = pk(a, bb);
  }
  __syncthreads();
  uint2* Pout = (uint2*)(ws + WS_P_OFF);
#pragma unroll 2
  for (int p = 0; p < 64; ++p) {
    float a0 = bias[0], a1 = bias[1], a2 = bias[2], a3 = bias[3];
#pragma unroll
    for (int j = 0; j < 14; ++j) {
      h2t xx = bc2(sX[p][j]);
      a0 = fdot2f(bc2(wih[0][j]), xx, a0);
      a1 = fdot2f(bc2(wih[1][j]), xx, a1);
      a2 = fdot2f(bc2(wih[2][j]), xx, a2);
      a3 = fdot2f(bc2(wih[3][j]), xx, a3);
    }
    uint2 o; o.x = pk(a0, a1); o.y = pk(a2, a3);
    Pout[((size_t)t * 128 + (b0 + p)) * 256 + u] = o;
  }
}

// Persistent LSTM scan. grid=128 (one block per batch element), 512 threads,
// 2 waves/SIMD. Thread v: half=v>>8 (k-half), u=v&255 (hidden unit).
__global__ __launch_bounds__(512, 2) void scan_k(
    const unsigned char* __restrict__ ws, const float* __restrict__ W_fc,
    const float* __restrict__ b_fc, float* __restrict__ out) {
  __shared__ u32x4 sWq[7 * 512];               // 57,344 B LDS-resident weights
  __shared__ u32x4 sHq[2][32];                 // h double buffer (128 h2)
  __shared__ float4 sAcc[256];                 // high->low partial exchange
  __shared__ float sHF[256];                   // final h fp32 for head
  const int v = threadIdx.x;
  const int b = blockIdx.x;
  const int half = v >> 8;
  const int u = v & 255;

  // --- tier 1: VGPR weights, pinned so they cannot be demoted to re-loads ---
  u32x4 wr[42];
  {
    const u32x4* wsc = (const u32x4*)(ws + WS_WSCAN_OFF);
#pragma unroll
    for (int f = 0; f < 42; ++f) wr[f] = wsc[f * 512 + v];
#pragma unroll
    for (int f = 0; f < 42; ++f) asm volatile("" : "+v"(wr[f]));
  }
  // --- tier 2: LDS weights ---
  {
    const u32x4* wld = (const u32x4*)(ws + WS_WLDS_OFF);
#pragma unroll
    for (int fl = 0; fl < 7; ++fl) sWq[fl * 512 + v] = wld[fl * 512 + v];
  }
  const u32x4* wstr = (const u32x4*)(ws + WS_WSTR_OFF);

  if (v < 64) {
    u32x4 z = {0u, 0u, 0u, 0u};
    ((u32x4*)sHq)[v] = z;                      // both h buffers = 0
  }
  const uint2* Pbuf = (const uint2*)(ws + WS_P_OFF);
  uint2 pP = make_uint2(0u, 0u);
  if (half == 0) pP = Pbuf[(size_t)b * 256 + u];
  float c = 0.f, hval = 0.f;
  __syncthreads();

#pragma unroll 1
  for (int t = 0; t < 512; ++t) {
    // --- tier 3: streamed weights (L2-resident, coalesced 16 B/lane) ---
    u32x4 tw[15];
#pragma unroll
    for (int i = 0; i < 8; ++i) tw[i] = wstr[i * 512 + v];

    const u32x4* rd = &sHq[t & 1][half << 4];
    float acc0 = 0.f, acc1 = 0.f, acc2 = 0.f, acc3 = 0.f;
#pragma unroll
    for (int q = 0; q < 5; ++q) {
      u32x4 hq = rd[q];
      acc0 = dot4(wr[q * 4 + 0], hq, acc0);
      acc1 = dot4(wr[q * 4 + 1], hq, acc1);
      acc2 = dot4(wr[q * 4 + 2], hq, acc2);
      acc3 = dot4(wr[q * 4 + 3], hq, acc3);
    }
#pragma unroll
    for (int i = 8; i < 15; ++i) tw[i] = wstr[i * 512 + v];
#pragma unroll
    for (int q = 5; q < 10; ++q) {
      u32x4 hq = rd[q];
      acc0 = dot4(wr[q * 4 + 0], hq, acc0);
      acc1 = dot4(wr[q * 4 + 1], hq, acc1);
      acc2 = dot4(wr[q * 4 + 2], hq, acc2);
      acc3 = dot4(wr[q * 4 + 3], hq, acc3);
    }
    {  // q=10: gates 0,1 VGPR; gates 2,3 LDS
      u32x4 hq = rd[10];
      acc0 = dot4(wr[40], hq, acc0);
      acc1 = dot4(wr[41], hq, acc1);
      acc2 = dot4(sWq[0 * 512 + v], hq, acc2);
      acc3 = dot4(sWq[1 * 512 + v], hq, acc3);
    }
    {  // q=11: all gates LDS
      u32x4 hq = rd[11];
      acc0 = dot4(sWq[2 * 512 + v], hq, acc0);
      acc1 = dot4(sWq[3 * 512 + v], hq, acc1);
      acc2 = dot4(sWq[4 * 512 + v], hq, acc2);
      acc3 = dot4(sWq[5 * 512 + v], hq, acc3);
    }
    {  // q=12: gate 0 LDS; gates 1..3 streamed
      u32x4 hq = rd[12];
      acc0 = dot4(sWq[6 * 512 + v], hq, acc0);
      acc1 = dot4(tw[0], hq, acc1);
      acc2 = dot4(tw[1], hq, acc2);
      acc3 = dot4(tw[2], hq, acc3);
    }
    {  // q=13..15: streamed
      u32x4 hq = rd[13];
      acc0 = dot4(tw[3], hq, acc0);
      acc1 = dot4(tw[4], hq, acc1);
      acc2 = dot4(tw[5], hq, acc2);
      acc3 = dot4(tw[6], hq, acc3);
    }
    {
      u32x4 hq = rd[14];
      acc0 = dot4(tw[7], hq, acc0);
      acc1 = dot4(tw[8], hq, acc1);
      acc2 = dot4(tw[9], hq, acc2);
      acc3 = dot4(tw[10], hq, acc3);
    }
    {
      u32x4 hq = rd[15];
      acc0 = dot4(tw[11], hq, acc0);
      acc1 = dot4(tw[12], hq, acc1);
      acc2 = dot4(tw[13], hq, acc2);
      acc3 = dot4(tw[14], hq, acc3);
    }

    uint2 pPn = pP;
    if (half) {
      sAcc[u] = make_float4(acc0, acc1, acc2, acc3);
    } else {
      int tn = (t < 511) ? (t + 1) : 511;
      pPn = Pbuf[((size_t)tn * 128 + b) * 256 + u];
    }
    __syncthreads();                           // sAcc visible; sH reads done

    if (!half) {
      float4 oth = sAcc[u];
      h2t p01 = bc2(pP.x), p23 = bc2(pP.y);
      float gi = acc0 + oth.x + (float)p01[0];
      float gf = acc1 + oth.y + (float)p01[1];
      float gg = acc2 + oth.z + (float)p23[0];
      float go = acc3 + oth.w + (float)p23[1];
      c = sigmf_(gf) * c + sigmf_(gi) * tanhf_(gg);
      hval = sigmf_(go) * tanhf_(c);
      ((_Float16*)(&sHq[(t + 1) & 1][0]))[u] = (_Float16)hval;
    }
    pP = pPn;
    __syncthreads();                           // h_{t+1} visible
  }

  // --- classifier head on final h ---
  if (!half) sHF[u] = hval;
  __syncthreads();
  if (v < 128) {
    const float4* wrow = (const float4*)(W_fc + (size_t)v * 256);
    float a = b_fc[v];
#pragma unroll 8
    for (int q = 0; q < 64; ++q) {
      float4 w = wrow[q];
      float4 hh = ((const float4*)sHF)[q];
      a += w.x * hh.x + w.y * hh.y + w.z * hh.z + w.w * hh.w;
    }
    out[(size_t)b * 128 + v] = a;
  }
}

extern "C" void kernel_launch(void* const* d_in, const int* in_sizes, int n_in,
                              void* d_out, int out_size, void* d_ws,
                              size_t ws_size, hipStream_t stream) {
  const float* x    = (const float*)d_in[0];
  // d_in[1] = input_lengths: unused by the reference
  const float* W_ih = (const float*)d_in[2];
  const float* W_hh = (const float*)d_in[3];
  const float* b_ih = (const float*)d_in[4];
  const float* b_hh = (const float*)d_in[5];
  // d_in[6] = W_xi, d_in[7] = b_xi: dead code in the reference
  const float* W_fc = (const float*)d_in[8];
  const float* b_fc = (const float*)d_in[9];
  unsigned char* ws = (unsigned char*)d_ws;

  if (ws_size < WS_NEED) return;  // signature: output stays poisoned

  prep_w<<<512, 256, 0, stream>>>(W_hh, ws);
  prep_p<<<1024, 256, 0, stream>>>(x, W_ih, b_ih, b_hh, ws);
  scan_k<<<128, 512, 0, stream>>>(ws, W_fc, b_fc, (float*)d_out);
}

// Round 4
// 899.007 us; speedup vs baseline: 1.8752x; 1.0042x over previous
//
#include <hip/hip_runtime.h>
#include <hip/hip_fp16.h>

// DNCClassifier: DNC memory machinery is dead code (inputs built with the
// initial zero read vector); output = LSTM-final-h @ W_fc.T + b_fc.
//   gates_t = x_t @ W_ih[:, :27].T + (b_ih + b_hh) + h @ W_hh.T
// Sizes: B=128, T=512, IN=27, H=256 (4H=1024), OUT=128.
//
// R4: R2/R3 showed the GCN scheduler ignores __launch_bounds__ min-waves and
// chases 4-waves/EU occupancy (VGPR_Count=128), demoting resident weights to
// per-step L2 reloads (R2) or AGPR round-trips (R3). Fix:
//   - amdgpu_waves_per_eu(2,2) clamps occupancy at exactly 2 waves/EU ->
//     256-VGPR budget with no incentive to shrink.
//   - re-tier 64 weight quads/thread: 54 VGPR (216 regs) + 7 LDS (57 KB)
//     + 3 streamed/step (12 live regs only; R3's 15-quad stream held 60).
//   - no asm pins (they induced AGPR copies in R3).
// Step floor: 256 dot2/thread x 2 waves/SIMD x 2 cyc = 1024 cyc/SIMD.
// Flat weight-quad id f = q*4+g (q = h-quad 0..15 within K-half, g = gate):
// f<54 VGPR, 54..60 LDS, 61..63 streamed. k2=(v>>8)*64+4q+e, row=g*256+(v&255).

typedef _Float16 h2t __attribute__((ext_vector_type(2)));
typedef unsigned int u32x4 __attribute__((ext_vector_type(4)));

#if defined(__has_builtin)
#  if __has_builtin(__builtin_amdgcn_fdot2)
#    define HAVE_FDOT2 1
#  endif
#endif

__device__ __forceinline__ h2t bc2(unsigned int v) {
  union { unsigned int u; h2t h; } x; x.u = v; return x.h;
}
__device__ __forceinline__ unsigned int pk(float a, float b) {
  union { h2t h; unsigned int u; } x;
  x.h[0] = (_Float16)a; x.h[1] = (_Float16)b;
  return x.u;
}
__device__ __forceinline__ float fdot2f(h2t a, h2t b, float c) {
#ifdef HAVE_FDOT2
  return __builtin_amdgcn_fdot2(a, b, c, false);
#else
  return c + (float)a[0] * (float)b[0] + (float)a[1] * (float)b[1];
#endif
}
__device__ __forceinline__ float dot4(u32x4 w, u32x4 h, float a) {
  a = fdot2f(bc2(w[0]), bc2(h[0]), a);
  a = fdot2f(bc2(w[1]), bc2(h[1]), a);
  a = fdot2f(bc2(w[2]), bc2(h[2]), a);
  a = fdot2f(bc2(w[3]), bc2(h[3]), a);
  return a;
}
__device__ __forceinline__ float sigmf_(float x) {
  return 1.f / (1.f + __expf(-x));
}
__device__ __forceinline__ float tanhf_(float x) {
  float xc = fminf(15.f, fmaxf(-15.f, x));
  float e = __expf(2.f * xc);
  return (e - 1.f) / (e + 1.f);
}

// ---- workspace layout (bytes) ----
// P      : [(t*128+b)*256+u] uint2 (gates i,f,g,o fp16, bias folded in)
// Wscan  : u32x4[f *512+v], f  = 0..53  -> VGPR-resident
// Wlds   : u32x4[fl*512+v], fl = f-54, f = 54..60 -> LDS-resident
// Wstr   : u32x4[fs*512+v], fs = f-61, f = 61..63 -> streamed per step
#define WS_P_OFF      0ull
#define WS_WSCAN_OFF  134217728ull   // 54*512*16 = 442368
#define WS_WLDS_OFF   134660096ull   // 7*512*16  = 57344
#define WS_WSTR_OFF   134717440ull   // 3*512*16  = 24576
#define WS_NEED       134742016ull

__global__ void prep_w(const float* __restrict__ W_hh,
                       unsigned char* __restrict__ ws) {
  int idx = blockIdx.x * 256 + threadIdx.x;   // 512 blocks -> idx < 131072
  unsigned int* dst; int j, f;
  if (idx < 110592) {                         // Wscan: 54*512*4 uints
    j = idx; dst = (unsigned int*)(ws + WS_WSCAN_OFF); f = (j >> 2) >> 9;
  } else if (idx < 124928) {                  // Wlds: 7*512*4 uints
    j = idx - 110592; dst = (unsigned int*)(ws + WS_WLDS_OFF);
    f = 54 + ((j >> 2) >> 9);
  } else {                                    // Wstr: 3*512*4 uints
    j = idx - 124928; dst = (unsigned int*)(ws + WS_WSTR_OFF);
    f = 61 + ((j >> 2) >> 9);
  }
  int e = j & 3, v = (j >> 2) & 511;
  int q = f >> 2, g = f & 3;
  int k2 = ((v >> 8) << 6) + 4 * q + e;
  int r = g * 256 + (v & 255);
  dst[j] = pk(W_hh[r * 256 + 2 * k2], W_hh[r * 256 + 2 * k2 + 1]);
}

// P[t,b,u,:] = bias(u,:) + x[b,t,:27] @ W_ih[:, :27].T  (fp16x4 out)
// grid 1024: block handles one t (= blockIdx>>1) x 64 b's. x staged up front.
__global__ __launch_bounds__(256) void prep_p(const float* __restrict__ x,
                                              const float* __restrict__ W_ih,
                                              const float* __restrict__ b_ih,
                                              const float* __restrict__ b_hh,
                                              unsigned char* __restrict__ ws) {
  __shared__ unsigned int sX[64][14];
  const int u = threadIdx.x;
  const int t = blockIdx.x >> 1;
  const int b0 = (blockIdx.x & 1) << 6;
  unsigned int wih[4][14];
  float bias[4];
#pragma unroll
  for (int g = 0; g < 4; ++g) {
    const float* row = W_ih + (size_t)(g * 256 + u) * 47;
    bias[g] = b_ih[g * 256 + u] + b_hh[g * 256 + u];
#pragma unroll
    for (int j = 0; j < 14; ++j) {
      float a = row[2 * j];
      float b = (2 * j + 1 < 27) ? row[2 * j + 1] : 0.f;
      wih[g][j] = pk(a, b);
    }
  }
#pragma unroll 1
  for (int j = u; j < 896; j += 256) {        // stage 64 rows of x
    int row = j / 14, c2 = j - 14 * row;
    const float* xr = x + ((size_t)(b0 + row) * 512 + t) * 27;
    float a = xr[2 * c2];
    float bb = (2 * c2 + 1 < 27) ? xr[2 * c2 + 1] : 0.f;
    sX[row][c2] = pk(a, bb);
  }
  __syncthreads();
  uint2* Pout = (uint2*)(ws + WS_P_OFF);
#pragma unroll 2
  for (int p = 0; p < 64; ++p) {
    float a0 = bias[0], a1 = bias[1], a2 = bias[2], a3 = bias[3];
#pragma unroll
    for (int j = 0; j < 14; ++j) {
      h2t xx = bc2(sX[p][j]);
      a0 = fdot2f(bc2(wih[0][j]), xx, a0);
      a1 = fdot2f(bc2(wih[1][j]), xx, a1);
      a2 = fdot2f(bc2(wih[2][j]), xx, a2);
      a3 = fdot2f(bc2(wih[3][j]), xx, a3);
    }
    uint2 o; o.x = pk(a0, a1); o.y = pk(a2, a3);
    Pout[((size_t)t * 128 + (b0 + p)) * 256 + u] = o;
  }
}

// Persistent LSTM scan. grid=128 (one block per batch element), 512 threads,
// exactly 2 waves/SIMD (clamped). Thread v: half=v>>8 (K-half), u=v&255 (unit).
__attribute__((amdgpu_flat_work_group_size(512, 512), amdgpu_waves_per_eu(2, 2)))
__global__ void scan_k(
    const unsigned char* __restrict__ ws, const float* __restrict__ W_fc,
    const float* __restrict__ b_fc, float* __restrict__ out) {
  __shared__ u32x4 sWq[7 * 512];               // 57,344 B LDS-resident weights
  __shared__ u32x4 sHq[2][32];                 // h double buffer (128 h2)
  __shared__ float4 sAcc[256];                 // high->low partial exchange
  __shared__ float sHF[256];                   // final h fp32 for head
  const int v = threadIdx.x;
  const int b = blockIdx.x;
  const int half = v >> 8;
  const int u = v & 255;

  // --- tier 1: VGPR-resident weights (54 quads = 216 regs) ---
  u32x4 wr[54];
  {
    const u32x4* wsc = (const u32x4*)(ws + WS_WSCAN_OFF);
#pragma unroll
    for (int f = 0; f < 54; ++f) wr[f] = wsc[f * 512 + v];
  }
  // --- tier 2: LDS-resident weights (7 quads) ---
  {
    const u32x4* wld = (const u32x4*)(ws + WS_WLDS_OFF);
#pragma unroll
    for (int fl = 0; fl < 7; ++fl) sWq[fl * 512 + v] = wld[fl * 512 + v];
  }
  const u32x4* wstr = (const u32x4*)(ws + WS_WSTR_OFF);

  if (v < 64) {
    u32x4 z = {0u, 0u, 0u, 0u};
    ((u32x4*)sHq)[v] = z;                      // both h buffers = 0
  }
  const uint2* Pbuf = (const uint2*)(ws + WS_P_OFF);
  uint2 pP = make_uint2(0u, 0u);
  if (half == 0) pP = Pbuf[(size_t)b * 256 + u];
  float c = 0.f, hval = 0.f;
  __syncthreads();

#pragma unroll 1
  for (int t = 0; t < 512; ++t) {
    // --- tier 3: streamed weights (3 quads, L2-resident, 12 live regs) ---
    u32x4 tw0 = wstr[0 * 512 + v];
    u32x4 tw1 = wstr[1 * 512 + v];
    u32x4 tw2 = wstr[2 * 512 + v];

    const u32x4* rd = &sHq[t & 1][half << 4];
    float acc0 = 0.f, acc1 = 0.f, acc2 = 0.f, acc3 = 0.f;
#pragma unroll
    for (int q = 0; q < 13; ++q) {             // f = 4q+g, all VGPR (f<52)
      u32x4 hq = rd[q];
      acc0 = dot4(wr[q * 4 + 0], hq, acc0);
      acc1 = dot4(wr[q * 4 + 1], hq, acc1);
      acc2 = dot4(wr[q * 4 + 2], hq, acc2);
      acc3 = dot4(wr[q * 4 + 3], hq, acc3);
    }
    {  // q=13: f=52,53 VGPR; f=54,55 LDS
      u32x4 hq = rd[13];
      acc0 = dot4(wr[52], hq, acc0);
      acc1 = dot4(wr[53], hq, acc1);
      acc2 = dot4(sWq[0 * 512 + v], hq, acc2);
      acc3 = dot4(sWq[1 * 512 + v], hq, acc3);
    }
    {  // q=14: f=56..59 LDS
      u32x4 hq = rd[14];
      acc0 = dot4(sWq[2 * 512 + v], hq, acc0);
      acc1 = dot4(sWq[3 * 512 + v], hq, acc1);
      acc2 = dot4(sWq[4 * 512 + v], hq, acc2);
      acc3 = dot4(sWq[5 * 512 + v], hq, acc3);
    }
    {  // q=15: f=60 LDS; f=61..63 streamed
      u32x4 hq = rd[15];
      acc0 = dot4(sWq[6 * 512 + v], hq, acc0);
      acc1 = dot4(tw0, hq, acc1);
      acc2 = dot4(tw1, hq, acc2);
      acc3 = dot4(tw2, hq, acc3);
    }

    uint2 pPn = pP;
    if (half) {
      sAcc[u] = make_float4(acc0, acc1, acc2, acc3);
    } else {
      int tn = (t < 511) ? (t + 1) : 511;
      pPn = Pbuf[((size_t)tn * 128 + b) * 256 + u];
    }
    __syncthreads();                           // sAcc visible; sH reads done

    if (!half) {
      float4 oth = sAcc[u];
      h2t p01 = bc2(pP.x), p23 = bc2(pP.y);
      float gi = acc0 + oth.x + (float)p01[0];
      float gf = acc1 + oth.y + (float)p01[1];
      float gg = acc2 + oth.z + (float)p23[0];
      float go = acc3 + oth.w + (float)p23[1];
      c = sigmf_(gf) * c + sigmf_(gi) * tanhf_(gg);
      hval = sigmf_(go) * tanhf_(c);
      ((_Float16*)(&sHq[(t + 1) & 1][0]))[u] = (_Float16)hval;
    }
    pP = pPn;
    __syncthreads();                           // h_{t+1} visible
  }

  // --- classifier head on final h ---
  if (!half) sHF[u] = hval;
  __syncthreads();
  if (v < 128) {
    const float4* wrow = (const float4*)(W_fc + (size_t)v * 256);
    float a = b_fc[v];
#pragma unroll 8
    for (int q = 0; q < 64; ++q) {
      float4 w = wrow[q];
      float4 hh = ((const float4*)sHF)[q];
      a += w.x * hh.x + w.y * hh.y + w.z * hh.z + w.w * hh.w;
    }
    out[(size_t)b * 128 + v] = a;
  }
}

extern "C" void kernel_launch(void* const* d_in, const int* in_sizes, int n_in,
                              void* d_out, int out_size, void* d_ws,
                              size_t ws_size, hipStream_t stream) {
  const float* x    = (const float*)d_in[0];
  // d_in[1] = input_lengths: unused by the reference
  const float* W_ih = (const float*)d_in[2];
  const float* W_hh = (const float*)d_in[3];
  const float* b_ih = (const float*)d_in[4];
  const float* b_hh = (const float*)d_in[5];
  // d_in[6] = W_xi, d_in[7] = b_xi: dead code in the reference
  const float* W_fc = (const float*)d_in[8];
  const float* b_fc = (const float*)d_in[9];
  unsigned char* ws = (unsigned char*)d_ws;

  if (ws_size < WS_NEED) return;  // signature: output stays poisoned

  prep_w<<<512, 256, 0, stream>>>(W_hh, ws);
  prep_p<<<1024, 256, 0, stream>>>(x, W_ih, b_ih, b_hh, ws);
  scan_k<<<128, 512, 0, stream>>>(ws, W_fc, b_fc, (float*)d_out);
}